// Round 3
// baseline (523.152 us; speedup 1.0000x reference)
//
#include <hip/hip_runtime.h>

typedef unsigned short ushort_t;
typedef __bf16 bf16x8 __attribute__((ext_vector_type(8)));
typedef float f32x4 __attribute__((ext_vector_type(4)));

__device__ __forceinline__ ushort_t f2bf(float f) {
  union { float f; unsigned u; } x;
  x.f = f;
  unsigned r = x.u + 0x7fffu + ((x.u >> 16) & 1u);
  return (ushort_t)(r >> 16);
}

// ---------------------------------------------------------------------------
// Transpose fp32 -> bf16: out[n][k] = bf16(in[k][n]).  in: [K][N] fp32.
// Grid: (N/64, K/64), 256 threads.
// ---------------------------------------------------------------------------
__global__ __launch_bounds__(256) void transpose_f32_bf16(const float* __restrict__ in,
                                                          ushort_t* __restrict__ out,
                                                          int K, int N) {
  __shared__ ushort_t s[64][72];
  const int n0 = blockIdx.x * 64, k0 = blockIdx.y * 64;
  const int r = threadIdx.x >> 2;
  const int c = (threadIdx.x & 3) * 16;
  const float* src = in + (size_t)(k0 + r) * N + n0 + c;
  float buf[16];
#pragma unroll
  for (int i = 0; i < 16; i += 4) *(float4*)&buf[i] = *(const float4*)(src + i);
  ushort_t t[16];
#pragma unroll
  for (int i = 0; i < 16; ++i) t[i] = f2bf(buf[i]);
  *(uint4*)&s[r][c] = *(const uint4*)&t[0];
  *(uint4*)&s[r][c + 8] = *(const uint4*)&t[8];
  __syncthreads();
  ushort_t tmp[16];
#pragma unroll
  for (int i = 0; i < 16; ++i) tmp[i] = s[c + i][r];  // in[k0+c+i][n0+r]
  ushort_t* dst = out + (size_t)(n0 + r) * K + k0 + c;
  *(uint4*)&dst[0] = *(const uint4*)&tmp[0];
  *(uint4*)&dst[8] = *(const uint4*)&tmp[8];
}

// ---------------------------------------------------------------------------
// GEMM1: qkv = x @ w_qkv.  A: [8192][768] fp32 (converted to bf16 on stage).
// Bt: [2304][768] bf16 (w_qkv transposed).  Scatters into qkv[3][24][4096][64].
// Tile 64x64, BK=32, 4 waves (2x2), each wave 32x32 via 2x2 MFMA 16x16x32.
// Grid: (128, 36), 256 threads.
// ---------------------------------------------------------------------------
__global__ __launch_bounds__(256) void gemm_qkv_kernel(const float* __restrict__ A,
                                                       const ushort_t* __restrict__ Bt,
                                                       ushort_t* __restrict__ qkv) {
  constexpr int K = 768;
  __shared__ ushort_t sA[64][40];
  __shared__ ushort_t sB[64][40];
  const int tid = threadIdx.x;
  const int lane = tid & 63, w = tid >> 6;
  const int wm = w >> 1, wn = w & 1;
  const int col = lane & 15, quad = lane >> 4;
  const int ldr = tid >> 2;        // 0..63
  const int ldc = (tid & 3) * 8;   // 0,8,16,24
  const int m0 = blockIdx.x * 64, n0 = blockIdx.y * 64;
  f32x4 acc[2][2] = {};
  const float* aptr = A + (size_t)(m0 + ldr) * K + ldc;
  const ushort_t* bptr = Bt + (size_t)(n0 + ldr) * K + ldc;
  for (int k0 = 0; k0 < K; k0 += 32) {
    float4 u0 = *(const float4*)(aptr + k0);
    float4 u1 = *(const float4*)(aptr + k0 + 4);
    ushort_t t[8];
    t[0] = f2bf(u0.x); t[1] = f2bf(u0.y); t[2] = f2bf(u0.z); t[3] = f2bf(u0.w);
    t[4] = f2bf(u1.x); t[5] = f2bf(u1.y); t[6] = f2bf(u1.z); t[7] = f2bf(u1.w);
    *(uint4*)&sA[ldr][ldc] = *(const uint4*)&t[0];
    *(uint4*)&sB[ldr][ldc] = *(const uint4*)(bptr + k0);
    __syncthreads();
    bf16x8 af0 = *(const bf16x8*)&sA[wm * 32 + col][quad * 8];
    bf16x8 af1 = *(const bf16x8*)&sA[wm * 32 + 16 + col][quad * 8];
    bf16x8 bf0 = *(const bf16x8*)&sB[wn * 32 + col][quad * 8];
    bf16x8 bf1 = *(const bf16x8*)&sB[wn * 32 + 16 + col][quad * 8];
    acc[0][0] = __builtin_amdgcn_mfma_f32_16x16x32_bf16(af0, bf0, acc[0][0], 0, 0, 0);
    acc[0][1] = __builtin_amdgcn_mfma_f32_16x16x32_bf16(af0, bf1, acc[0][1], 0, 0, 0);
    acc[1][0] = __builtin_amdgcn_mfma_f32_16x16x32_bf16(af1, bf0, acc[1][0], 0, 0, 0);
    acc[1][1] = __builtin_amdgcn_mfma_f32_16x16x32_bf16(af1, bf1, acc[1][1], 0, 0, 0);
    __syncthreads();
  }
#pragma unroll
  for (int mt = 0; mt < 2; ++mt)
#pragma unroll
    for (int nt = 0; nt < 2; ++nt)
#pragma unroll
      for (int r = 0; r < 4; ++r) {
        int m = m0 + wm * 32 + mt * 16 + quad * 4 + r;  // C/D: row = quad*4+r
        int n = n0 + wn * 32 + nt * 16 + col;           //      col = lane&15
        int which = n / 768;
        int rem = n - which * 768;
        int h = rem >> 6, d = rem & 63;
        int b = m >> 12, s = m & 4095;
        qkv[(((size_t)(which * 24 + b * 12 + h) * 4096 + s) << 6) + d] =
            f2bf(acc[mt][nt][r]);
      }
}

// ---------------------------------------------------------------------------
// Flash attention, causal.  One block = one (b,h) and one 64-row Q tile.
// qkv layout [3][24][4096][64] bf16.  ctx out: [B][S][768] bf16.
// Grid: (64, 24), 256 threads (4 waves; wave w owns Q rows w*16..w*16+15).
// ---------------------------------------------------------------------------
__global__ __launch_bounds__(256) void flash_kernel(const ushort_t* __restrict__ qkv,
                                                    ushort_t* __restrict__ ctx) {
  constexpr int S = 4096;
  constexpr int HD = 64;
  const int qt = (int)gridDim.x - 1 - (int)blockIdx.x;  // longest-first
  const int bh = blockIdx.y;
  const int b = bh / 12, h = bh - b * 12;

  const ushort_t* Qp = qkv + (size_t)bh * S * HD;
  const ushort_t* Kp = qkv + (size_t)(24 + bh) * S * HD;
  const ushort_t* Vp = qkv + (size_t)(48 + bh) * S * HD;

  __shared__ ushort_t sQ[64][72];
  __shared__ ushort_t sK[64][72];
  __shared__ ushort_t sVt[64][72];      // sVt[d][key]
  __shared__ ushort_t sP[4][16][72];    // per-wave P strip

  const int tid = threadIdx.x;
  const int lane = tid & 63, w = tid >> 6;
  const int col = lane & 15, quad = lane >> 4;
  const int ldr = tid >> 2;        // 0..63
  const int ldc = (tid & 3) * 16;  // 0,16,32,48

  {
    const ushort_t* src = Qp + (size_t)(qt * 64 + ldr) * HD + ldc;
    *(uint4*)&sQ[ldr][ldc] = *(const uint4*)src;
    *(uint4*)&sQ[ldr][ldc + 8] = *(const uint4*)(src + 8);
  }
  __syncthreads();
  // A-frag: lane -> Q[m = lane&15][k = quad*8+j]
  bf16x8 qf0 = *(const bf16x8*)&sQ[w * 16 + col][quad * 8];
  bf16x8 qf1 = *(const bf16x8*)&sQ[w * 16 + col][32 + quad * 8];

  float m_i[4], l_i[4];
  f32x4 o[4] = {};
#pragma unroll
  for (int r = 0; r < 4; ++r) { m_i[r] = -1e30f; l_i[r] = 0.f; }

  for (int jt = 0; jt <= qt; ++jt) {
    __syncthreads();  // prior iteration's readers done before restaging
    {
      const ushort_t* ks = Kp + (size_t)(jt * 64 + ldr) * HD + ldc;
      *(uint4*)&sK[ldr][ldc] = *(const uint4*)ks;
      *(uint4*)&sK[ldr][ldc + 8] = *(const uint4*)(ks + 8);
      const ushort_t* vs = Vp + (size_t)(jt * 64 + ldr) * HD + ldc;
      ushort_t tmp[16];
      *(uint4*)&tmp[0] = *(const uint4*)vs;
      *(uint4*)&tmp[8] = *(const uint4*)(vs + 8);
#pragma unroll
      for (int i = 0; i < 16; ++i) sVt[ldc + i][ldr] = tmp[i];
    }
    __syncthreads();

    // S = Q K^T  (B-frag of K^T == A-style read of row-major K)
    f32x4 sc[4];
#pragma unroll
    for (int nt = 0; nt < 4; ++nt) {
      bf16x8 kf0 = *(const bf16x8*)&sK[nt * 16 + col][quad * 8];
      bf16x8 kf1 = *(const bf16x8*)&sK[nt * 16 + col][32 + quad * 8];
      f32x4 z = {0.f, 0.f, 0.f, 0.f};
      z = __builtin_amdgcn_mfma_f32_16x16x32_bf16(qf0, kf0, z, 0, 0, 0);
      z = __builtin_amdgcn_mfma_f32_16x16x32_bf16(qf1, kf1, z, 0, 0, 0);
      sc[nt] = z;
    }

    float p[4][4];
    const bool diag = (jt == qt);
#pragma unroll
    for (int nt = 0; nt < 4; ++nt)
#pragma unroll
      for (int r = 0; r < 4; ++r) {
        float v = sc[nt][r] * 0.125f;  // 1/sqrt(64)
        if (diag && (nt * 16 + col > w * 16 + quad * 4 + r)) v = -1e30f;
        p[nt][r] = v;
      }

    // online softmax per row (row = quad*4+r; reduce over the 16 col-lanes)
#pragma unroll
    for (int r = 0; r < 4; ++r) {
      float t = fmaxf(fmaxf(p[0][r], p[1][r]), fmaxf(p[2][r], p[3][r]));
      t = fmaxf(t, __shfl_xor(t, 1));
      t = fmaxf(t, __shfl_xor(t, 2));
      t = fmaxf(t, __shfl_xor(t, 4));
      t = fmaxf(t, __shfl_xor(t, 8));
      float mnew = fmaxf(m_i[r], t);
      float alpha = __expf(m_i[r] - mnew);
      m_i[r] = mnew;
      float rs = 0.f;
#pragma unroll
      for (int nt = 0; nt < 4; ++nt) {
        float e = __expf(p[nt][r] - mnew);
        p[nt][r] = e;
        rs += e;
      }
      rs += __shfl_xor(rs, 1);
      rs += __shfl_xor(rs, 2);
      rs += __shfl_xor(rs, 4);
      rs += __shfl_xor(rs, 8);
      l_i[r] = l_i[r] * alpha + rs;
#pragma unroll
      for (int dt = 0; dt < 4; ++dt) o[dt][r] *= alpha;
    }

    // P: C-layout -> LDS -> A-layout (per-wave private strip)
#pragma unroll
    for (int nt = 0; nt < 4; ++nt)
#pragma unroll
      for (int r = 0; r < 4; ++r)
        sP[w][quad * 4 + r][nt * 16 + col] = f2bf(p[nt][r]);
    __syncthreads();
    bf16x8 pf0 = *(const bf16x8*)&sP[w][col][quad * 8];
    bf16x8 pf1 = *(const bf16x8*)&sP[w][col][32 + quad * 8];
#pragma unroll
    for (int dt = 0; dt < 4; ++dt) {
      bf16x8 vf0 = *(const bf16x8*)&sVt[dt * 16 + col][quad * 8];
      bf16x8 vf1 = *(const bf16x8*)&sVt[dt * 16 + col][32 + quad * 8];
      o[dt] = __builtin_amdgcn_mfma_f32_16x16x32_bf16(pf0, vf0, o[dt], 0, 0, 0);
      o[dt] = __builtin_amdgcn_mfma_f32_16x16x32_bf16(pf1, vf1, o[dt], 0, 0, 0);
    }
  }

#pragma unroll
  for (int dt = 0; dt < 4; ++dt)
#pragma unroll
    for (int r = 0; r < 4; ++r) {
      int q = qt * 64 + w * 16 + quad * 4 + r;
      float val = o[dt][r] / l_i[r];
      ctx[((size_t)(b * S + q)) * 768 + h * 64 + dt * 16 + col] = f2bf(val);
    }
}

// ---------------------------------------------------------------------------
// GEMM2: out = ctx @ w_out.  A: [8192][768] bf16, Bt: [768][768] bf16,
// out: [8192][768] fp32 (reference output dtype).  Grid: (128, 12).
// ---------------------------------------------------------------------------
__global__ __launch_bounds__(256) void gemm_out_kernel(const ushort_t* __restrict__ A,
                                                       const ushort_t* __restrict__ Bt,
                                                       float* __restrict__ out) {
  constexpr int K = 768;
  __shared__ ushort_t sA[64][40];
  __shared__ ushort_t sB[64][40];
  const int tid = threadIdx.x;
  const int lane = tid & 63, w = tid >> 6;
  const int wm = w >> 1, wn = w & 1;
  const int col = lane & 15, quad = lane >> 4;
  const int ldr = tid >> 2;
  const int ldc = (tid & 3) * 8;
  const int m0 = blockIdx.x * 64, n0 = blockIdx.y * 64;
  f32x4 acc[2][2] = {};
  const ushort_t* aptr = A + (size_t)(m0 + ldr) * K + ldc;
  const ushort_t* bptr = Bt + (size_t)(n0 + ldr) * K + ldc;
  for (int k0 = 0; k0 < K; k0 += 32) {
    *(uint4*)&sA[ldr][ldc] = *(const uint4*)(aptr + k0);
    *(uint4*)&sB[ldr][ldc] = *(const uint4*)(bptr + k0);
    __syncthreads();
    bf16x8 af0 = *(const bf16x8*)&sA[wm * 32 + col][quad * 8];
    bf16x8 af1 = *(const bf16x8*)&sA[wm * 32 + 16 + col][quad * 8];
    bf16x8 bf0 = *(const bf16x8*)&sB[wn * 32 + col][quad * 8];
    bf16x8 bf1 = *(const bf16x8*)&sB[wn * 32 + 16 + col][quad * 8];
    acc[0][0] = __builtin_amdgcn_mfma_f32_16x16x32_bf16(af0, bf0, acc[0][0], 0, 0, 0);
    acc[0][1] = __builtin_amdgcn_mfma_f32_16x16x32_bf16(af0, bf1, acc[0][1], 0, 0, 0);
    acc[1][0] = __builtin_amdgcn_mfma_f32_16x16x32_bf16(af1, bf0, acc[1][0], 0, 0, 0);
    acc[1][1] = __builtin_amdgcn_mfma_f32_16x16x32_bf16(af1, bf1, acc[1][1], 0, 0, 0);
    __syncthreads();
  }
#pragma unroll
  for (int mt = 0; mt < 2; ++mt)
#pragma unroll
    for (int nt = 0; nt < 2; ++nt)
#pragma unroll
      for (int r = 0; r < 4; ++r) {
        int m = m0 + wm * 32 + mt * 16 + quad * 4 + r;
        int n = n0 + wn * 32 + nt * 16 + col;
        out[(size_t)m * 768 + n] = acc[mt][nt][r];  // fp32 output
      }
}

// ---------------------------------------------------------------------------
extern "C" void kernel_launch(void* const* d_in, const int* in_sizes, int n_in,
                              void* d_out, int out_size, void* d_ws, size_t ws_size,
                              hipStream_t stream) {
  (void)in_sizes; (void)n_in; (void)out_size; (void)ws_size;
  const float* x = (const float*)d_in[0];       // [2][4096][768] fp32
  const float* w_qkv = (const float*)d_in[1];   // [768][2304] fp32
  const float* w_out = (const float*)d_in[2];   // [768][768] fp32
  float* out = (float*)d_out;                   // [2][4096][768] fp32

  ushort_t* ws = (ushort_t*)d_ws;
  ushort_t* wqkv_t = ws;                                 // 2304*768 bf16
  ushort_t* wout_t = wqkv_t + 2304 * 768;                // 768*768 bf16
  ushort_t* qkv = wout_t + 768 * 768;                    // 3*24*4096*64 bf16
  ushort_t* ctx = qkv + 3 * 24 * 4096 * 64;              // 8192*768 bf16
  // total ws: ~55 MB

  transpose_f32_bf16<<<dim3(36, 12), 256, 0, stream>>>(w_qkv, wqkv_t, 768, 2304);
  transpose_f32_bf16<<<dim3(12, 12), 256, 0, stream>>>(w_out, wout_t, 768, 768);
  gemm_qkv_kernel<<<dim3(128, 36), 256, 0, stream>>>(x, wqkv_t, qkv);
  flash_kernel<<<dim3(64, 24), 256, 0, stream>>>(qkv, ctx);
  gemm_out_kernel<<<dim3(128, 12), 256, 0, stream>>>(ctx, wout_t, out);
}

// Round 4
// 417.538 us; speedup vs baseline: 1.2529x; 1.2529x over previous
//
#include <hip/hip_runtime.h>

typedef unsigned short ushort_t;
typedef __bf16 bf16x8 __attribute__((ext_vector_type(8)));
typedef float f32x4 __attribute__((ext_vector_type(4)));

__device__ __forceinline__ ushort_t f2bf(float f) {
  union { float f; unsigned u; } x;
  x.f = f;
  unsigned r = x.u + 0x7fffu + ((x.u >> 16) & 1u);
  return (ushort_t)(r >> 16);
}

// DPP reduction over each 16-lane row (lanes q*16..q*16+15 share a C-row).
__device__ __forceinline__ float row_max16(float x) {
  float y;
  y = __int_as_float(__builtin_amdgcn_update_dpp(
      __float_as_int(x), __float_as_int(x), 0xB1, 0xF, 0xF, false));  // quad xor1
  x = fmaxf(x, y);
  y = __int_as_float(__builtin_amdgcn_update_dpp(
      __float_as_int(x), __float_as_int(x), 0x4E, 0xF, 0xF, false));  // quad xor2
  x = fmaxf(x, y);
  y = __int_as_float(__builtin_amdgcn_update_dpp(
      __float_as_int(x), __float_as_int(x), 0x141, 0xF, 0xF, false)); // half mirror
  x = fmaxf(x, y);
  y = __int_as_float(__builtin_amdgcn_update_dpp(
      __float_as_int(x), __float_as_int(x), 0x140, 0xF, 0xF, false)); // row mirror
  x = fmaxf(x, y);
  return x;
}
__device__ __forceinline__ float row_sum16(float x) {
  float y;
  y = __int_as_float(__builtin_amdgcn_update_dpp(
      __float_as_int(x), __float_as_int(x), 0xB1, 0xF, 0xF, false));
  x += y;
  y = __int_as_float(__builtin_amdgcn_update_dpp(
      __float_as_int(x), __float_as_int(x), 0x4E, 0xF, 0xF, false));
  x += y;
  y = __int_as_float(__builtin_amdgcn_update_dpp(
      __float_as_int(x), __float_as_int(x), 0x141, 0xF, 0xF, false));
  x += y;
  y = __int_as_float(__builtin_amdgcn_update_dpp(
      __float_as_int(x), __float_as_int(x), 0x140, 0xF, 0xF, false));
  x += y;
  return x;
}

// ---------------------------------------------------------------------------
// Transpose fp32 -> bf16: out[n][k] = bf16(in[k][n]).  in: [K][N] fp32.
// Grid: (N/64, K/64), 256 threads.
// ---------------------------------------------------------------------------
__global__ __launch_bounds__(256) void transpose_f32_bf16(const float* __restrict__ in,
                                                          ushort_t* __restrict__ out,
                                                          int K, int N) {
  __shared__ ushort_t s[64][72];
  const int n0 = blockIdx.x * 64, k0 = blockIdx.y * 64;
  const int r = threadIdx.x >> 2;
  const int c = (threadIdx.x & 3) * 16;
  const float* src = in + (size_t)(k0 + r) * N + n0 + c;
  float buf[16];
#pragma unroll
  for (int i = 0; i < 16; i += 4) *(float4*)&buf[i] = *(const float4*)(src + i);
  ushort_t t[16];
#pragma unroll
  for (int i = 0; i < 16; ++i) t[i] = f2bf(buf[i]);
  *(uint4*)&s[r][c] = *(const uint4*)&t[0];
  *(uint4*)&s[r][c + 8] = *(const uint4*)&t[8];
  __syncthreads();
  ushort_t tmp[16];
#pragma unroll
  for (int i = 0; i < 16; ++i) tmp[i] = s[c + i][r];  // in[k0+c+i][n0+r]
  ushort_t* dst = out + (size_t)(n0 + r) * K + k0 + c;
  *(uint4*)&dst[0] = *(const uint4*)&tmp[0];
  *(uint4*)&dst[8] = *(const uint4*)&tmp[8];
}

// ---------------------------------------------------------------------------
// Per-head V transpose: v_t[bh][d][s] = v[bh][s][d].  v: qkv slab 2.
// Grid: (64, 24), 256 threads.
// ---------------------------------------------------------------------------
__global__ __launch_bounds__(256) void transpose_v(const ushort_t* __restrict__ v,
                                                   ushort_t* __restrict__ v_t) {
  __shared__ ushort_t s[64][72];
  const int s0 = blockIdx.x * 64;
  const int bh = blockIdx.y;
  const ushort_t* src = v + ((size_t)bh * 4096 + s0) * 64;
  ushort_t* dst = v_t + (size_t)bh * 64 * 4096 + s0;
  const int r = threadIdx.x >> 2;        // seq within tile
  const int c = (threadIdx.x & 3) * 16;  // d chunk
  *(uint4*)&s[r][c] = *(const uint4*)(src + (size_t)r * 64 + c);
  *(uint4*)&s[r][c + 8] = *(const uint4*)(src + (size_t)r * 64 + c + 8);
  __syncthreads();
  ushort_t tmp[16];
#pragma unroll
  for (int i = 0; i < 16; ++i) tmp[i] = s[c + i][r];  // v[s0+c+i][d=r]
  *(uint4*)&dst[(size_t)r * 4096 + c] = *(const uint4*)&tmp[0];
  *(uint4*)&dst[(size_t)r * 4096 + c + 8] = *(const uint4*)&tmp[8];
}

// ---------------------------------------------------------------------------
// GEMM1: qkv = x @ w_qkv.  A: [8192][768] fp32 (converted to bf16 on stage).
// Bt: [2304][768] bf16.  Scatters into qkv[3][24][4096][64].
// Grid: (128, 36), 256 threads.
// ---------------------------------------------------------------------------
__global__ __launch_bounds__(256) void gemm_qkv_kernel(const float* __restrict__ A,
                                                       const ushort_t* __restrict__ Bt,
                                                       ushort_t* __restrict__ qkv) {
  constexpr int K = 768;
  __shared__ ushort_t sA[64][40];
  __shared__ ushort_t sB[64][40];
  const int tid = threadIdx.x;
  const int lane = tid & 63, w = tid >> 6;
  const int wm = w >> 1, wn = w & 1;
  const int col = lane & 15, quad = lane >> 4;
  const int ldr = tid >> 2;
  const int ldc = (tid & 3) * 8;
  const int m0 = blockIdx.x * 64, n0 = blockIdx.y * 64;
  f32x4 acc[2][2] = {};
  const float* aptr = A + (size_t)(m0 + ldr) * K + ldc;
  const ushort_t* bptr = Bt + (size_t)(n0 + ldr) * K + ldc;
  for (int k0 = 0; k0 < K; k0 += 32) {
    float4 u0 = *(const float4*)(aptr + k0);
    float4 u1 = *(const float4*)(aptr + k0 + 4);
    ushort_t t[8];
    t[0] = f2bf(u0.x); t[1] = f2bf(u0.y); t[2] = f2bf(u0.z); t[3] = f2bf(u0.w);
    t[4] = f2bf(u1.x); t[5] = f2bf(u1.y); t[6] = f2bf(u1.z); t[7] = f2bf(u1.w);
    *(uint4*)&sA[ldr][ldc] = *(const uint4*)&t[0];
    *(uint4*)&sB[ldr][ldc] = *(const uint4*)(bptr + k0);
    __syncthreads();
    bf16x8 af0 = *(const bf16x8*)&sA[wm * 32 + col][quad * 8];
    bf16x8 af1 = *(const bf16x8*)&sA[wm * 32 + 16 + col][quad * 8];
    bf16x8 bf0 = *(const bf16x8*)&sB[wn * 32 + col][quad * 8];
    bf16x8 bf1 = *(const bf16x8*)&sB[wn * 32 + 16 + col][quad * 8];
    acc[0][0] = __builtin_amdgcn_mfma_f32_16x16x32_bf16(af0, bf0, acc[0][0], 0, 0, 0);
    acc[0][1] = __builtin_amdgcn_mfma_f32_16x16x32_bf16(af0, bf1, acc[0][1], 0, 0, 0);
    acc[1][0] = __builtin_amdgcn_mfma_f32_16x16x32_bf16(af1, bf0, acc[1][0], 0, 0, 0);
    acc[1][1] = __builtin_amdgcn_mfma_f32_16x16x32_bf16(af1, bf1, acc[1][1], 0, 0, 0);
    __syncthreads();
  }
#pragma unroll
  for (int mt = 0; mt < 2; ++mt)
#pragma unroll
    for (int nt = 0; nt < 2; ++nt)
#pragma unroll
      for (int r = 0; r < 4; ++r) {
        int m = m0 + wm * 32 + mt * 16 + quad * 4 + r;
        int n = n0 + wn * 32 + nt * 16 + col;
        int which = n / 768;
        int rem = n - which * 768;
        int h = rem >> 6, d = rem & 63;
        int b = m >> 12, s = m & 4095;
        qkv[(((size_t)(which * 24 + b * 12 + h) * 4096 + s) << 6) + d] =
            f2bf(acc[mt][nt][r]);
      }
}

// ---------------------------------------------------------------------------
// Flash attention, causal.  One block = one (b,h) and one 64-row Q tile.
// qkv [3][24][4096][64] bf16; v_t [24][64][4096] bf16; ctx [B][S][768] bf16.
// Grid: (64, 24), 256 threads.  LDS 27648 B -> 5 blocks/CU.
// ---------------------------------------------------------------------------
__global__ __launch_bounds__(256) void flash_kernel(const ushort_t* __restrict__ qkv,
                                                    const ushort_t* __restrict__ v_t,
                                                    ushort_t* __restrict__ ctx) {
  constexpr int S = 4096;
  constexpr int HD = 64;
  constexpr float SCL = 0.1803368801111137f;  // (1/sqrt(64)) * log2(e)
  const int qt = (int)gridDim.x - 1 - (int)blockIdx.x;  // longest-first
  const int bh = blockIdx.y;
  const int b = bh / 12, h = bh - b * 12;

  const ushort_t* Qp = qkv + (size_t)bh * S * HD;
  const ushort_t* Kp = qkv + (size_t)(24 + bh) * S * HD;
  const ushort_t* Vt = v_t + (size_t)bh * HD * S;

  __shared__ ushort_t sK[64][72];
  __shared__ ushort_t sVt[64][72];                 // sVt[d][key]
  __shared__ ushort_t sQP[64][72];                 // sQ, then aliased as sP[4][16][72]

  const int tid = threadIdx.x;
  const int lane = tid & 63, w = tid >> 6;
  const int col = lane & 15, quad = lane >> 4;
  const int ldr = tid >> 2;        // 0..63
  const int ldc = (tid & 3) * 16;  // 0,16,32,48

  {
    const ushort_t* src = Qp + (size_t)(qt * 64 + ldr) * HD + ldc;
    *(uint4*)&sQP[ldr][ldc] = *(const uint4*)src;
    *(uint4*)&sQP[ldr][ldc + 8] = *(const uint4*)(src + 8);
  }
  __syncthreads();
  // A-frag: lane -> Q[m = lane&15][k = quad*8+j]
  bf16x8 qf0 = *(const bf16x8*)&sQP[w * 16 + col][quad * 8];
  bf16x8 qf1 = *(const bf16x8*)&sQP[w * 16 + col][32 + quad * 8];
  ushort_t (*sP)[72] = (ushort_t(*)[72])&sQP[w * 16][0];  // per-wave 16x72 strip

  float m_i[4], l_i[4];
  f32x4 o[4] = {};
#pragma unroll
  for (int r = 0; r < 4; ++r) { m_i[r] = -1e30f; l_i[r] = 0.f; }

  for (int jt = 0; jt <= qt; ++jt) {
    __syncthreads();  // prior readers (incl. qf loads on iter 0) done
    {
      const ushort_t* ks = Kp + (size_t)(jt * 64 + ldr) * HD + ldc;
      *(uint4*)&sK[ldr][ldc] = *(const uint4*)ks;
      *(uint4*)&sK[ldr][ldc + 8] = *(const uint4*)(ks + 8);
      const ushort_t* vs = Vt + (size_t)ldr * S + jt * 64 + ldc;  // row d=ldr
      *(uint4*)&sVt[ldr][ldc] = *(const uint4*)vs;
      *(uint4*)&sVt[ldr][ldc + 8] = *(const uint4*)(vs + 8);
    }
    __syncthreads();

    // S = Q K^T
    f32x4 sc[4];
#pragma unroll
    for (int nt = 0; nt < 4; ++nt) {
      bf16x8 kf0 = *(const bf16x8*)&sK[nt * 16 + col][quad * 8];
      bf16x8 kf1 = *(const bf16x8*)&sK[nt * 16 + col][32 + quad * 8];
      f32x4 z = {0.f, 0.f, 0.f, 0.f};
      z = __builtin_amdgcn_mfma_f32_16x16x32_bf16(qf0, kf0, z, 0, 0, 0);
      z = __builtin_amdgcn_mfma_f32_16x16x32_bf16(qf1, kf1, z, 0, 0, 0);
      sc[nt] = z;
    }

    float p[4][4];  // log2-domain scores
    const bool diag = (jt == qt);
#pragma unroll
    for (int nt = 0; nt < 4; ++nt)
#pragma unroll
      for (int r = 0; r < 4; ++r) {
        float v = sc[nt][r] * SCL;
        if (diag && (nt * 16 + col > w * 16 + quad * 4 + r)) v = -1e30f;
        p[nt][r] = v;
      }

    // online softmax per row (row = quad*4+r; reduce over 16-lane row group)
#pragma unroll
    for (int r = 0; r < 4; ++r) {
      float t = fmaxf(fmaxf(p[0][r], p[1][r]), fmaxf(p[2][r], p[3][r]));
      t = row_max16(t);
      float mnew = fmaxf(m_i[r], t);
      float alpha = __builtin_amdgcn_exp2f(m_i[r] - mnew);
      m_i[r] = mnew;
      float rs = 0.f;
#pragma unroll
      for (int nt = 0; nt < 4; ++nt) {
        float e = __builtin_amdgcn_exp2f(p[nt][r] - mnew);
        p[nt][r] = e;
        rs += e;
      }
      rs = row_sum16(rs);
      l_i[r] = l_i[r] * alpha + rs;
#pragma unroll
      for (int dt = 0; dt < 4; ++dt) o[dt][r] *= alpha;
    }

    // P: C-layout -> LDS -> A-layout (per-wave strip aliasing sQ)
#pragma unroll
    for (int nt = 0; nt < 4; ++nt)
#pragma unroll
      for (int r = 0; r < 4; ++r)
        sP[quad * 4 + r][nt * 16 + col] = f2bf(p[nt][r]);
    __syncthreads();
    bf16x8 pf0 = *(const bf16x8*)&sP[col][quad * 8];
    bf16x8 pf1 = *(const bf16x8*)&sP[col][32 + quad * 8];
#pragma unroll
    for (int dt = 0; dt < 4; ++dt) {
      bf16x8 vf0 = *(const bf16x8*)&sVt[dt * 16 + col][quad * 8];
      bf16x8 vf1 = *(const bf16x8*)&sVt[dt * 16 + col][32 + quad * 8];
      o[dt] = __builtin_amdgcn_mfma_f32_16x16x32_bf16(pf0, vf0, o[dt], 0, 0, 0);
      o[dt] = __builtin_amdgcn_mfma_f32_16x16x32_bf16(pf1, vf1, o[dt], 0, 0, 0);
    }
  }

#pragma unroll
  for (int dt = 0; dt < 4; ++dt)
#pragma unroll
    for (int r = 0; r < 4; ++r) {
      int q = qt * 64 + w * 16 + quad * 4 + r;
      float val = o[dt][r] / l_i[r];
      ctx[((size_t)(b * S + q)) * 768 + h * 64 + dt * 16 + col] = f2bf(val);
    }
}

// ---------------------------------------------------------------------------
// GEMM2: out = ctx @ w_out.  A: [8192][768] bf16, Bt: [768][768] bf16,
// out: [8192][768] fp32.  Grid: (128, 12).
// ---------------------------------------------------------------------------
__global__ __launch_bounds__(256) void gemm_out_kernel(const ushort_t* __restrict__ A,
                                                       const ushort_t* __restrict__ Bt,
                                                       float* __restrict__ out) {
  constexpr int K = 768;
  __shared__ ushort_t sA[64][40];
  __shared__ ushort_t sB[64][40];
  const int tid = threadIdx.x;
  const int lane = tid & 63, w = tid >> 6;
  const int wm = w >> 1, wn = w & 1;
  const int col = lane & 15, quad = lane >> 4;
  const int ldr = tid >> 2;
  const int ldc = (tid & 3) * 8;
  const int m0 = blockIdx.x * 64, n0 = blockIdx.y * 64;
  f32x4 acc[2][2] = {};
  const ushort_t* aptr = A + (size_t)(m0 + ldr) * K + ldc;
  const ushort_t* bptr = Bt + (size_t)(n0 + ldr) * K + ldc;
  for (int k0 = 0; k0 < K; k0 += 32) {
    *(uint4*)&sA[ldr][ldc] = *(const uint4*)(aptr + k0);
    *(uint4*)&sB[ldr][ldc] = *(const uint4*)(bptr + k0);
    __syncthreads();
    bf16x8 af0 = *(const bf16x8*)&sA[wm * 32 + col][quad * 8];
    bf16x8 af1 = *(const bf16x8*)&sA[wm * 32 + 16 + col][quad * 8];
    bf16x8 bf0 = *(const bf16x8*)&sB[wn * 32 + col][quad * 8];
    bf16x8 bf1 = *(const bf16x8*)&sB[wn * 32 + 16 + col][quad * 8];
    acc[0][0] = __builtin_amdgcn_mfma_f32_16x16x32_bf16(af0, bf0, acc[0][0], 0, 0, 0);
    acc[0][1] = __builtin_amdgcn_mfma_f32_16x16x32_bf16(af0, bf1, acc[0][1], 0, 0, 0);
    acc[1][0] = __builtin_amdgcn_mfma_f32_16x16x32_bf16(af1, bf0, acc[1][0], 0, 0, 0);
    acc[1][1] = __builtin_amdgcn_mfma_f32_16x16x32_bf16(af1, bf1, acc[1][1], 0, 0, 0);
    __syncthreads();
  }
#pragma unroll
  for (int mt = 0; mt < 2; ++mt)
#pragma unroll
    for (int nt = 0; nt < 2; ++nt)
#pragma unroll
      for (int r = 0; r < 4; ++r) {
        int m = m0 + wm * 32 + mt * 16 + quad * 4 + r;
        int n = n0 + wn * 32 + nt * 16 + col;
        out[(size_t)m * 768 + n] = acc[mt][nt][r];
      }
}

// ---------------------------------------------------------------------------
extern "C" void kernel_launch(void* const* d_in, const int* in_sizes, int n_in,
                              void* d_out, int out_size, void* d_ws, size_t ws_size,
                              hipStream_t stream) {
  (void)in_sizes; (void)n_in; (void)out_size; (void)ws_size;
  const float* x = (const float*)d_in[0];       // [2][4096][768] fp32
  const float* w_qkv = (const float*)d_in[1];   // [768][2304] fp32
  const float* w_out = (const float*)d_in[2];   // [768][768] fp32
  float* out = (float*)d_out;                   // [2][4096][768] fp32

  ushort_t* ws = (ushort_t*)d_ws;
  ushort_t* wqkv_t = ws;                                 // 2304*768 bf16
  ushort_t* wout_t = wqkv_t + 2304 * 768;                // 768*768 bf16
  ushort_t* qkv = wout_t + 768 * 768;                    // 3*24*4096*64 bf16
  ushort_t* v_t = qkv + 3 * 24 * 4096 * 64;              // 24*64*4096 bf16
  ushort_t* ctx = v_t + 24 * 64 * 4096;                  // 8192*768 bf16
  // total ws: ~67 MB

  transpose_f32_bf16<<<dim3(36, 12), 256, 0, stream>>>(w_qkv, wqkv_t, 768, 2304);
  transpose_f32_bf16<<<dim3(12, 12), 256, 0, stream>>>(w_out, wout_t, 768, 768);
  gemm_qkv_kernel<<<dim3(128, 36), 256, 0, stream>>>(x, wqkv_t, qkv);
  transpose_v<<<dim3(64, 24), 256, 0, stream>>>(qkv + (size_t)48 * 4096 * 64, v_t);
  flash_kernel<<<dim3(64, 24), 256, 0, stream>>>(qkv, v_t, ctx);
  gemm_out_kernel<<<dim3(128, 12), 256, 0, stream>>>(ctx, wout_t, out);
}